// Round 12
// baseline (30197.156 us; speedup 1.0000x reference)
//
#include <hip/hip_runtime.h>
#include <math.h>

#define B 32
#define S 512
#define T 128
#define V 32000
#define H 512
#define NB 256          // persistent grid size
#define NTE 512         // encoder threads (8 waves)
#define NTD 512         // decoder threads: 8 waves (row-partitioned phases -> no replication)
#define LCHUNK 250      // logits: 250 blocks x 128 rows
#define LROWS 128
#define XPITCH 520      // enc x/h staging pitch (floats), 16B-aligned

__device__ __forceinline__ float dot4(float acc, float4 a, float4 b){
    return fmaf(a.x,b.x, fmaf(a.y,b.y, fmaf(a.z,b.z, fmaf(a.w,b.w, acc))));
}
__device__ __forceinline__ float sigmoidf_(float x){ return 1.0f/(1.0f+expf(-x)); }

// ---- two-level grid barrier with separate broadcast (epoch) line -----------
// (harness-verified, round 2)
template<int GRPSZ>
__device__ __forceinline__ void gbar_arrive(unsigned* bb, unsigned grp, unsigned n){
    __syncthreads();
    if (threadIdx.x == 0){
        const unsigned r = __hip_atomic_fetch_add(bb + grp*32, 1u,
                              __ATOMIC_RELEASE, __HIP_MEMORY_SCOPE_AGENT);
        if (r == n*(unsigned)GRPSZ - 1u){
            const unsigned q = __hip_atomic_fetch_add(bb + 256, 1u,
                                  __ATOMIC_RELEASE, __HIP_MEMORY_SCOPE_AGENT);
            if (q == n*8u - 1u)
                __hip_atomic_store(bb + 288, n,
                                   __ATOMIC_RELEASE, __HIP_MEMORY_SCOPE_AGENT);
        }
    }
}
__device__ __forceinline__ void gbar_wait(unsigned* bb, unsigned n){
    if (threadIdx.x == 0){
        long guard = 0;
        while (__hip_atomic_load(bb + 288, __ATOMIC_RELAXED, __HIP_MEMORY_SCOPE_AGENT) < n){
            __builtin_amdgcn_s_sleep(2);
            if (++guard > 200000000L) break;
        }
        (void)__hip_atomic_load(bb + 288, __ATOMIC_ACQUIRE, __HIP_MEMORY_SCOPE_AGENT);
    }
    __syncthreads();
}

// ================= persistent encoder (r10, measured — unchanged) ============
__global__ __launch_bounds__(NTE, 1) void enc_persistent(
    const int* __restrict__ input_seq, const float* __restrict__ emb,
    const float* __restrict__ fWih, const float* __restrict__ fWhh,
    const float* __restrict__ fbih, const float* __restrict__ fbhh,
    const float* __restrict__ bWih, const float* __restrict__ bWhh,
    const float* __restrict__ bbih, const float* __restrict__ bbhh,
    float* enc_out, float* out_b, unsigned* bars)
{
    __shared__ float wlds[24*512];      // 48 KB weights
    __shared__ float shp[3*128*6];      // 9 KB partial exchange
    __shared__ float xh[32*XPITCH];     // 65 KB x/h row staging
    const int bk = blockIdx.x, tid = threadIdx.x;
    const int dir = bk & 1, jg = bk >> 1;
    const int b = tid & 31, jj = (tid>>5)&3, kh = tid>>7;
    const int j = jg*4 + jj;
    const unsigned grp = ((unsigned)jg) & 7u;

    const float *Wih = dir? bWih : fWih;
    const float *Whh = dir? bWhh : fWhh;
    const float *bih = dir? bbih : fbih;
    const float *bhh = dir? bbhh : fbhh;
    float* outp = dir? out_b : enc_out;
    unsigned* bar = bars + dir*1024;

    for (int r=0;r<24;r++){
        const int jr = jg*4 + (r/6);
        const int g  = r % 6;
        const float* src = (g<3) ? (Wih + ((size_t)g*H + jr)*H)
                                 : (Whh + ((size_t)(g-3)*H + jr)*H);
        for (int k=tid;k<H;k+=NTE) wlds[r*512+k] = src[k];
    }
    __syncthreads();

    const float4* wx0 = (const float4*)(wlds + (jj*6+0)*512 + kh*128);
    const float4* wx1 = (const float4*)(wlds + (jj*6+1)*512 + kh*128);
    const float4* wx2 = (const float4*)(wlds + (jj*6+2)*512 + kh*128);
    const float4* wh0 = (const float4*)(wlds + (jj*6+3)*512 + kh*128);
    const float4* wh1 = (const float4*)(wlds + (jj*6+4)*512 + kh*128);
    const float4* wh2 = (const float4*)(wlds + (jj*6+5)*512 + kh*128);
    const float bi_r = bih[j], bi_z = bih[H+j], bi_n = bih[2*H+j];
    const float bh_r = bhh[j], bh_z = bhh[H+j], bh_n = bhh[2*H+j];

    for (int t=0; t<S; t++){
        const int pos  = dir ? (S-1-t) : t;
        const int hpos = dir ? (S-t)   : (t-1);

        // ---- stage x rows (coalesced: 128 consecutive threads per row) ----
        #pragma unroll
        for (int it=0; it<8; ++it){
            const int idx = it*NTE + tid;
            const int bb = idx >> 7, c = idx & 127;
            const int tok = input_seq[bb*S + pos];
            ((float4*)(xh + bb*XPITCH))[c] =
                ((const float4*)(emb + (size_t)tok*H))[c];
        }
        __syncthreads();

        // x-part BEFORE the wait (overlaps barrier skew)
        float ir=0.f, iz=0.f, in_=0.f;
        {
            const float4* x4 = (const float4*)(xh + b*XPITCH + kh*128);
            #pragma unroll 8
            for (int k=0;k<32;k++){
                const float4 xv = x4[k];
                ir  = dot4(ir , xv, wx0[k]);
                iz  = dot4(iz , xv, wx1[k]);
                in_ = dot4(in_, xv, wx2[k]);
            }
        }

        if (t > 0) gbar_wait(bar, (unsigned)t);   // ends with __syncthreads

        float hr=0.f, hz=0.f, hn=0.f, hprev = 0.f;
        if (t > 0){
            // ---- stage h rows (coalesced) ----
            #pragma unroll
            for (int it=0; it<8; ++it){
                const int idx = it*NTE + tid;
                const int bb = idx >> 7, c = idx & 127;
                ((float4*)(xh + bb*XPITCH))[c] =
                    ((const float4*)(outp + ((size_t)bb*S + hpos)*H))[c];
            }
            __syncthreads();
            const float4* h4 = (const float4*)(xh + b*XPITCH + kh*128);
            #pragma unroll 8
            for (int k=0;k<32;k++){
                const float4 hv = h4[k];
                hr = dot4(hr, hv, wh0[k]);
                hz = dot4(hz, hv, wh1[k]);
                hn = dot4(hn, hv, wh2[k]);
            }
            hprev = xh[b*XPITCH + j];
        }
        if (kh){
            float* p = shp + ((kh-1)*128 + jj*32 + b)*6;
            p[0]=ir; p[1]=iz; p[2]=in_; p[3]=hr; p[4]=hz; p[5]=hn;
        }
        __syncthreads();
        if (!kh){
            #pragma unroll
            for (int q=0;q<3;q++){
                const float* p = shp + (q*128 + jj*32 + b)*6;
                ir+=p[0]; iz+=p[1]; in_+=p[2]; hr+=p[3]; hz+=p[4]; hn+=p[5];
            }
            const float r = sigmoidf_(ir + bi_r + hr + bh_r);
            const float z = sigmoidf_(iz + bi_z + hz + bh_z);
            const float n = tanhf(in_ + bi_n + r*(hn + bh_n));
            outp[((size_t)b*S + pos)*H + j] = (1.0f - z)*n + z*hprev;
        }
        gbar_arrive<16>(bar, grp, (unsigned)(t+1));
    }
}

// ================= persistent decoder: 8 waves, row-partitioned phases =======
__global__ __launch_bounds__(NTD, 1) void dec_persistent(
    const int* __restrict__ target_seq, const float* __restrict__ emb,
    const float* __restrict__ dWih, const float* __restrict__ dWhh,
    const float* __restrict__ dbih, const float* __restrict__ dbhh,
    const float* __restrict__ attW, const float* __restrict__ attb,
    const float* __restrict__ outW, const float* __restrict__ outBias,
    float* enc_out, const float* out_b,
    float* hdec, float* scores, float* ctxb, float* att_out,
    float* pm, float* ps, int* pidx, float* lossb,
    float* out, unsigned* bar)
{
    __shared__ __align__(16) float smem[128*33*4];      // 67.6 KB: L att-tile / scratch
    __shared__ float wg[12*512];                        // GRU weights: 2 j x 6 rows
    __shared__ float wp[2*1024];                        // proj weights: 2 rows x 2H
    __shared__ float red_m[8][32], red_s[8][32];        // phase-L cross-wave reduce
    __shared__ int   red_i[8][32];
    __shared__ int sh_tok[B];
    const int bk = blockIdx.x, tid = threadIdx.x;
    const unsigned grp = (unsigned)bk & 7u;
    unsigned bn = 1;
#define GSYNC() do { gbar_arrive<32>(bar, grp, bn); gbar_wait(bar, bn); ++bn; } while(0)

    // stage decoder weights -> LDS (once)
    for (int r=0;r<12;r++){
        const int jr = bk*2 + (r/6);
        const int g  = r % 6;
        const float* src = (g<3) ? (dWih + ((size_t)g*H + jr)*H)
                                 : (dWhh + ((size_t)(g-3)*H + jr)*H);
        for (int k=tid;k<H;k+=NTD) wg[r*512+k] = src[k];
    }
    for (int r=0;r<2;r++){
        const float* src = attW + (size_t)(bk*2+r)*(2*H);
        for (int k=tid;k<2*H;k+=NTD) wp[r*1024+k] = src[k];
    }

    // ---- phase A: hdec0 = hf_last + hb_last; loss init ----------------------
    {
        const int gid = bk*NTD + tid;
        if (gid < B*H){
            const int bb = gid >> 9, jq = gid & 511;
            hdec[gid] = enc_out[((size_t)bb*S + (S-1))*H + jq] + out_b[((size_t)bb*S)*H + jq];
        }
        if (bk==0 && tid<B) lossb[tid] = 0.0f;
    }
    GSYNC();

    // ---- phase B: combine enc_out += out_b ----------------------------------
    {
        float4* e4 = (float4*)enc_out; const float4* o4 = (const float4*)out_b;
        for (size_t i = (size_t)bk*NTD + tid; i < (size_t)B*S*H/4; i += (size_t)NB*NTD){
            float4 x = e4[i]; const float4 y = o4[i];
            x.x+=y.x; x.y+=y.y; x.z+=y.z; x.w+=y.w; e4[i]=x;
        }
    }
    GSYNC();

    const int gb = tid & 31, gj = (tid>>5)&1, gkq = tid>>6;   // gkq in 0..7
    const int jrow = bk*2 + gj;
    const float4* gwir = (const float4*)(wg + (gj*6+0)*512 + gkq*64);
    const float4* gwiz = (const float4*)(wg + (gj*6+1)*512 + gkq*64);
    const float4* gwin = (const float4*)(wg + (gj*6+2)*512 + gkq*64);
    const float4* gwhr = (const float4*)(wg + (gj*6+3)*512 + gkq*64);
    const float4* gwhz = (const float4*)(wg + (gj*6+4)*512 + gkq*64);
    const float4* gwhn = (const float4*)(wg + (gj*6+5)*512 + gkq*64);
    const float gbi_r = dbih[jrow], gbi_z = dbih[H+jrow], gbi_n = dbih[2*H+jrow];
    const float gbh_r = dbhh[jrow], gbh_z = dbhh[H+jrow], gbh_n = dbhh[2*H+jrow];
    const float4* pw = (const float4*)(wp + gj*1024 + gkq*128);

    for (int t=0; t<T; t++){
        float* hin  = hdec + (size_t)(t&1)*B*H;
        float* hout = hdec + (size_t)((t+1)&1)*B*H;

        // ---------- phase G: merge(t-1) -> tokens (+loss by blk0), then GRU --
        if (t == 0){
            if (tid < B) sh_tok[tid] = 1;     // SOS
        } else if (tid < 256) {
            const int mb = tid>>3, p = tid&7;
            float bv = -INFINITY; int ai = 0x7FFFFFFF;
            for (int c=p; c<LCHUNK; c+=8){
                const float v = pm[mb*LCHUNK + c];
                if (v > bv){ bv = v; ai = pidx[mb*LCHUNK + c]; }
            }
            #pragma unroll
            for (int m=1; m<8; m<<=1){
                const float ov = __shfl_xor(bv, m); const int oi = __shfl_xor(ai, m);
                if (ov > bv || (ov == bv && oi < ai)){ bv = ov; ai = oi; }
            }
            if (p==0) sh_tok[mb] = ai;
            if (bk == 0){
                float mm = -INFINITY;
                for (int c=p; c<LCHUNK; c+=8) mm = fmaxf(mm, pm[mb*LCHUNK+c]);
                #pragma unroll
                for (int m=1;m<8;m<<=1) mm = fmaxf(mm, __shfl_xor(mm, m));
                float se = 0.0f;
                for (int c=p; c<LCHUNK; c+=8) se += ps[mb*LCHUNK+c]*expf(pm[mb*LCHUNK+c]-mm);
                #pragma unroll
                for (int m=1;m<8;m<<=1) se += __shfl_xor(se, m);
                const int tg = target_seq[mb*T + (t-1)];
                const float4* ar = (const float4*)(att_out + (size_t)mb*H) + p*16;
                const float4* wr = (const float4*)(outW + (size_t)tg*H) + p*16;
                float d = 0.0f;
                #pragma unroll
                for (int k=0;k<16;k++) d = dot4(d, ar[k], wr[k]);
                #pragma unroll
                for (int m=1;m<8;m<<=1) d += __shfl_xor(d, m);
                if (p==0) lossb[mb] += (mm + logf(se)) - (d + outBias[tg]);
            }
        }
        __syncthreads();
        {   // GRU: 2 j per block, K split 8x64, weights from LDS
            const int tokb = sh_tok[gb];
            const float4* x4 = (const float4*)(emb + (size_t)tokb*H + gkq*64);
            const float4* h4 = (const float4*)(hin + (size_t)gb*H + gkq*64);
            float ir=0.f, iz=0.f, in_=0.f, hr=0.f, hz=0.f, hn=0.f;
            #pragma unroll
            for (int k=0;k<16;k++){
                const float4 xv = x4[k], hv = h4[k];
                ir  = dot4(ir , xv, gwir[k]);
                iz  = dot4(iz , xv, gwiz[k]);
                in_ = dot4(in_, xv, gwin[k]);
                hr  = dot4(hr , hv, gwhr[k]);
                hz  = dot4(hz , hv, gwhz[k]);
                hn  = dot4(hn , hv, gwhn[k]);
            }
            if (gkq){
                float* pp = smem + ((gkq-1)*64 + gj*32 + gb)*6;
                pp[0]=ir; pp[1]=iz; pp[2]=in_; pp[3]=hr; pp[4]=hz; pp[5]=hn;
            }
            __syncthreads();
            if (!gkq){
                #pragma unroll
                for (int q=0;q<7;q++){
                    const float* pp = smem + (q*64 + gj*32 + gb)*6;
                    ir+=pp[0]; iz+=pp[1]; in_+=pp[2]; hr+=pp[3]; hz+=pp[4]; hn+=pp[5];
                }
                const float r = sigmoidf_(ir + gbi_r + hr + gbh_r);
                const float z = sigmoidf_(iz + gbi_z + hz + gbh_z);
                const float n = tanhf(in_ + gbi_n + r*(hn + gbh_n));
                const float hprev = hin[(size_t)gb*H + jrow];
                hout[(size_t)gb*H + jrow] = (1.0f - z)*n + z*hprev;
            }
        }
        GSYNC();

        // ---------- phase S: 8 waves x 8 rows, coalesced row reads -----------
        {
            const int bS = bk & 31, sg = bk >> 5;
            if (tid < 128)
                ((float4*)smem)[tid] = ((const float4*)(hout + (size_t)bS*H))[tid];
            __syncthreads();
            const int w = tid >> 6, lane = tid & 63;
            const float4 h0 = ((const float4*)smem)[lane];
            const float4 h1 = ((const float4*)smem)[64 + lane];
            const int sbase = sg*64 + w*8;
            #pragma unroll
            for (int i=0;i<8;i+=2){
                const int sA = sbase + i, sB = sA + 1;
                const float4* eA = (const float4*)(enc_out + ((size_t)bS*S + sA)*H);
                const float4* eB = (const float4*)(enc_out + ((size_t)bS*S + sB)*H);
                const float4 a0 = eA[lane], a1 = eA[64+lane];
                const float4 b0 = eB[lane], b1 = eB[64+lane];
                float a = dot4(dot4(0.f, a0, h0), a1, h1);
                float b = dot4(dot4(0.f, b0, h0), b1, h1);
                #pragma unroll
                for (int m=1;m<64;m<<=1){ a += __shfl_xor(a, m); b += __shfl_xor(b, m); }
                if (lane == 0){ scores[bS*S + sA] = a; scores[bS*S + sB] = b; }
            }
        }
        GSYNC();

        // ---------- phase C: softmax + ctx (512 thr; 8-way s-split) ----------
        {
            const int bC = bk & 31, cg = bk >> 5;
            float* sh_w = smem; float* red = smem + 512; float* part = smem + 1024;
            const float s0 = scores[bC*S + tid];       // 512 threads cover S
            red[tid] = s0; __syncthreads();
            for (int off=256; off>0; off>>=1){ if (tid<off) red[tid]=fmaxf(red[tid],red[tid+off]); __syncthreads(); }
            const float M = red[0]; __syncthreads();
            const float e0 = expf(s0-M);
            red[tid] = e0; __syncthreads();
            for (int off=256; off>0; off>>=1){ if (tid<off) red[tid]+=red[tid+off]; __syncthreads(); }
            const float inv = 1.0f/red[0];
            __syncthreads();
            sh_w[tid] = e0*inv;
            __syncthreads();
            const int col = cg*64 + (tid & 63);
            const int sg2 = tid >> 6;                  // 0..7
            const float* Ec = enc_out + (size_t)bC*S*H + col;
            float ac0=0.f, ac1=0.f, ac2=0.f, ac3=0.f;
            #pragma unroll 4
            for (int i=0;i<64;i+=4){
                const int sA = sg2 + 8*i, sB = sA+8, sC = sA+16, sD = sA+24;
                const float vA = Ec[(size_t)sA*H], vB = Ec[(size_t)sB*H];
                const float vC = Ec[(size_t)sC*H], vD = Ec[(size_t)sD*H];
                ac0 = fmaf(sh_w[sA], vA, ac0);
                ac1 = fmaf(sh_w[sB], vB, ac1);
                ac2 = fmaf(sh_w[sC], vC, ac2);
                ac3 = fmaf(sh_w[sD], vD, ac3);
            }
            part[tid] = (ac0+ac1)+(ac2+ac3); __syncthreads();
            if (tid < 64){
                float v = 0.f;
                #pragma unroll
                for (int i=0;i<8;i++) v += part[tid + 64*i];
                ctxb[bC*512 + cg*64 + tid] = v;
            }
        }
        GSYNC();

        // ---------- phase P: att_out = tanh([ctx,hn] @ attW.T + attb) ---------
        {
            const float* act = (gkq < 4) ? (ctxb + (size_t)gb*512 + gkq*128)
                                         : (hout + (size_t)gb*H + (gkq-4)*128);
            const float4* a4 = (const float4*)act;
            float acc = 0.f;
            #pragma unroll
            for (int k=0;k<32;k++) acc = dot4(acc, a4[k], pw[k]);
            if (gkq){
                smem[(gkq-1)*64 + gj*32 + gb] = acc;
            }
            __syncthreads();
            if (!gkq){
                #pragma unroll
                for (int q=0;q<7;q++) acc += smem[q*64 + gj*32 + gb];
                att_out[(size_t)gb*H + jrow] = tanhf(acc + attb[jrow]);
            }
        }
        GSYNC();

        // ---------- phase L: 8 waves x 16 rows; 2-row/lane 2-stage pipeline --
        if (bk < LCHUNK){
            float4* sh4 = (float4*)smem;                 // [128][33] float4
            for (int idx = tid; idx < 32*128; idx += NTD){
                const int k4 = idx & 127, bb = idx >> 7; // coalesced gmem read
                sh4[k4*33 + bb] = ((const float4*)att_out)[(size_t)bb*128 + k4];
            }
            __syncthreads();
            const int wid = tid >> 6, lane = tid & 63;
            const int rl = lane & 7, bl = lane >> 3;
            const int r0 = bk*LROWS + wid*16 + rl*2;     // 2 contiguous rows/lane
            const float4* w0 = (const float4*)(outW + (size_t)(r0+0)*H);
            const float4* w1 = (const float4*)(outW + (size_t)(r0+1)*H);
            float acc[2][4];
            acc[0][0]=0.f; acc[0][1]=0.f; acc[0][2]=0.f; acc[0][3]=0.f;
            acc[1][0]=0.f; acc[1][1]=0.f; acc[1][2]=0.f; acc[1][3]=0.f;

            // 2-stage pipeline: chunk = 4 k-float4s (8 weight loads/stage).
            float4 A0[4],A1[4], B0[4],B1[4];
            #pragma unroll
            for (int kk=0;kk<4;kk++){ A0[kk]=w0[kk]; A1[kk]=w1[kk]; }
            for (int kc=0; kc<16; kc++){
                const int kbB = kc*8 + 4;
                #pragma unroll
                for (int kk=0;kk<4;kk++){ B0[kk]=w0[kbB+kk]; B1[kk]=w1[kbB+kk]; }
                #pragma unroll
                for (int kk=0;kk<4;kk++){
                    const int k = kc*8 + kk;
                    const float4 a0 = sh4[k*33 + bl*4 + 0];
                    const float4 a1 = sh4[k*33 + bl*4 + 1];
                    const float4 a2 = sh4[k*33 + bl*4 + 2];
                    const float4 a3 = sh4[k*33 + bl*4 + 3];
                    acc[0][0]=dot4(acc[0][0],A0[kk],a0); acc[0][1]=dot4(acc[0][1],A0[kk],a1);
                    acc[0][2]=dot4(acc[0][2],A0[kk],a2); acc[0][3]=dot4(acc[0][3],A0[kk],a3);
                    acc[1][0]=dot4(acc[1][0],A1[kk],a0); acc[1][1]=dot4(acc[1][1],A1[kk],a1);
                    acc[1][2]=dot4(acc[1][2],A1[kk],a2); acc[1][3]=dot4(acc[1][3],A1[kk],a3);
                }
                if (kc < 15){
                    const int kbA = kc*8 + 8;
                    #pragma unroll
                    for (int kk=0;kk<4;kk++){ A0[kk]=w0[kbA+kk]; A1[kk]=w1[kbA+kk]; }
                }
                #pragma unroll
                for (int kk=0;kk<4;kk++){
                    const int k = kc*8 + 4 + kk;
                    const float4 a0 = sh4[k*33 + bl*4 + 0];
                    const float4 a1 = sh4[k*33 + bl*4 + 1];
                    const float4 a2 = sh4[k*33 + bl*4 + 2];
                    const float4 a3 = sh4[k*33 + bl*4 + 3];
                    acc[0][0]=dot4(acc[0][0],B0[kk],a0); acc[0][1]=dot4(acc[0][1],B0[kk],a1);
                    acc[0][2]=dot4(acc[0][2],B0[kk],a2); acc[0][3]=dot4(acc[0][3],B0[kk],a3);
                    acc[1][0]=dot4(acc[1][0],B1[kk],a0); acc[1][1]=dot4(acc[1][1],B1[kk],a1);
                    acc[1][2]=dot4(acc[1][2],B1[kk],a2); acc[1][3]=dot4(acc[1][3],B1[kk],a3);
                }
            }

            const float bs0 = outBias[r0], bs1 = outBias[r0+1];
            #pragma unroll
            for (int j=0;j<4;j++){
                const float l0 = acc[0][j]+bs0, l1 = acc[1][j]+bs1;
                float M = l0; int bi = r0;                       // first-max tie-break
                if (l1 > M){ M=l1; bi=r0+1; }
                float Ssum = expf(l0-M)+expf(l1-M);
                #pragma unroll
                for (int m=1;m<8;m<<=1){                         // combine 8 rl lanes
                    const float oM = __shfl_xor(M, m);
                    const float oS = __shfl_xor(Ssum, m);
                    const int   oI = __shfl_xor(bi, m);
                    const float nM = fmaxf(M, oM);
                    const float nS = Ssum*expf(M-nM) + oS*expf(oM-nM);
                    if (oM > M || (oM == M && oI < bi)) bi = oI;
                    M = nM; Ssum = nS;
                }
                if (rl == 0){
                    red_m[wid][bl*4+j] = M;
                    red_s[wid][bl*4+j] = Ssum;
                    red_i[wid][bl*4+j] = bi;
                }
            }
            __syncthreads();
            if (tid < 32){                                       // combine 8 waves
                float M = red_m[0][tid], Ssum = red_s[0][tid]; int bi = red_i[0][tid];
                #pragma unroll
                for (int w=1; w<8; w++){
                    const float oM = red_m[w][tid], oS = red_s[w][tid]; const int oI = red_i[w][tid];
                    const float nM = fmaxf(M, oM);
                    const float nS = Ssum*expf(M-nM) + oS*expf(oM-nM);
                    if (oM > M || (oM == M && oI < bi)) bi = oI;
                    M = nM; Ssum = nS;
                }
                pm[tid*LCHUNK + bk] = M;
                ps[tid*LCHUNK + bk] = Ssum;
                pidx[tid*LCHUNK + bk] = bi;
            }
        }
        GSYNC();
    }

    // ---- epilogue: block 0 computes loss(T-1) and the final mean -------------
    if (bk == 0){
        if (tid < 256){
            const int mb = tid>>3, p = tid&7;
            float mm = -INFINITY;
            for (int c=p; c<LCHUNK; c+=8) mm = fmaxf(mm, pm[mb*LCHUNK+c]);
            #pragma unroll
            for (int m=1;m<8;m<<=1) mm = fmaxf(mm, __shfl_xor(mm, m));
            float se = 0.0f;
            for (int c=p; c<LCHUNK; c+=8) se += ps[mb*LCHUNK+c]*expf(pm[mb*LCHUNK+c]-mm);
            #pragma unroll
            for (int m=1;m<8;m<<=1) se += __shfl_xor(se, m);
            const int tg = target_seq[mb*T + (T-1)];
            const float4* ar = (const float4*)(att_out + (size_t)mb*H) + p*16;
            const float4* wr = (const float4*)(outW + (size_t)tg*H) + p*16;
            float d = 0.0f;
            #pragma unroll
            for (int k=0;k<16;k++) d = dot4(d, ar[k], wr[k]);
            #pragma unroll
            for (int m=1;m<8;m<<=1) d += __shfl_xor(d, m);
            if (p==0) lossb[mb] += (mm + logf(se)) - (d + outBias[tg]);
        }
        __syncthreads();
        if (tid < B){
            float v = lossb[tid];
            for (int off=16; off>0; off>>=1) v += __shfl_down(v, off);
            if (tid == 0) out[0] = v / (float)(B*T);
        }
    }
#undef GSYNC
}

extern "C" void kernel_launch(void* const* d_in, const int* in_sizes, int n_in,
                              void* d_out, int out_size, void* d_ws, size_t ws_size,
                              hipStream_t stream)
{
    const int*   input_seq  = (const int*)  d_in[0];
    const int*   target_seq = (const int*)  d_in[1];
    const float* emb    = (const float*)d_in[2];
    const float* efWih  = (const float*)d_in[3];
    const float* efWhh  = (const float*)d_in[4];
    const float* efbih  = (const float*)d_in[5];
    const float* efbhh  = (const float*)d_in[6];
    const float* ebWih  = (const float*)d_in[7];
    const float* ebWhh  = (const float*)d_in[8];
    const float* ebbih  = (const float*)d_in[9];
    const float* ebbhh  = (const float*)d_in[10];
    const float* dWih   = (const float*)d_in[11];
    const float* dWhh   = (const float*)d_in[12];
    const float* dbih   = (const float*)d_in[13];
    const float* dbhh   = (const float*)d_in[14];
    const float* attW   = (const float*)d_in[15];
    const float* attb   = (const float*)d_in[16];
    const float* outW   = (const float*)d_in[17];
    const float* outBias= (const float*)d_in[18];

    // workspace layout (floats); barrier region = 3 instances x 1024 uints
    float* ws      = (float*)d_ws;
    unsigned* bars = (unsigned*)ws;
    float* enc_out = ws + 4096;                             // B*S*H
    float* outb    = enc_out + (size_t)B*S*H;               // B*S*H
    float* scores  = outb    + (size_t)B*S*H;               // B*S
    float* ctxb    = scores  + (size_t)B*S;                 // B*512
    float* attout  = ctxb    + (size_t)B*512;               // B*H
    float* pm      = attout  + (size_t)B*H;                 // B*LCHUNK
    float* ps      = pm      + (size_t)B*LCHUNK;            // B*LCHUNK
    int*   pidx    = (int*)(ps + (size_t)B*LCHUNK);         // B*LCHUNK
    float* hdec    = (float*)(pidx + (size_t)B*LCHUNK);     // 2*B*H
    float* lossb   = hdec    + (size_t)2*B*H;               // B

    hipMemsetAsync(bars, 0, 16384, stream);

    enc_persistent<<<NB, NTE, 0, stream>>>(input_seq, emb,
        efWih, efWhh, efbih, efbhh, ebWih, ebWhh, ebbih, ebbhh,
        enc_out, outb, bars);

    dec_persistent<<<NB, NTD, 0, stream>>>(target_seq, emb,
        dWih, dWhh, dbih, dbhh, attW, attb, outW, outBias,
        enc_out, outb, hdec, scores, ctxb, attout,
        pm, ps, pidx, lossb, (float*)d_out, bars + 2048);
}

// Round 13
// 26413.477 us; speedup vs baseline: 1.1432x; 1.1432x over previous
//
#include <hip/hip_runtime.h>
#include <math.h>

#define B 32
#define S 512
#define T 128
#define V 32000
#define H 512
#define NB 256          // persistent grid size
#define NTE 512         // encoder threads (8 waves)
#define NTD 256         // decoder threads (4 waves; r11 measured best)
#define LCHUNK 250      // logits: 250 blocks x 128 rows
#define LROWS 128
#define NPIN 32         // outW rows pinned in LDS per block (wave 0's rows)
#define PINP 516        // pinned row pitch (floats): %8==4 -> 2 bank classes
#define XPITCH 520      // enc x/h staging pitch (floats), 16B-aligned

__device__ __forceinline__ float dot4(float acc, float4 a, float4 b){
    return fmaf(a.x,b.x, fmaf(a.y,b.y, fmaf(a.z,b.z, fmaf(a.w,b.w, acc))));
}
__device__ __forceinline__ float sigmoidf_(float x){ return 1.0f/(1.0f+expf(-x)); }

// ---- two-level grid barrier with separate broadcast (epoch) line -----------
// (harness-verified, round 2)
template<int GRPSZ>
__device__ __forceinline__ void gbar_arrive(unsigned* bb, unsigned grp, unsigned n){
    __syncthreads();
    if (threadIdx.x == 0){
        const unsigned r = __hip_atomic_fetch_add(bb + grp*32, 1u,
                              __ATOMIC_RELEASE, __HIP_MEMORY_SCOPE_AGENT);
        if (r == n*(unsigned)GRPSZ - 1u){
            const unsigned q = __hip_atomic_fetch_add(bb + 256, 1u,
                                  __ATOMIC_RELEASE, __HIP_MEMORY_SCOPE_AGENT);
            if (q == n*8u - 1u)
                __hip_atomic_store(bb + 288, n,
                                   __ATOMIC_RELEASE, __HIP_MEMORY_SCOPE_AGENT);
        }
    }
}
__device__ __forceinline__ void gbar_wait(unsigned* bb, unsigned n){
    if (threadIdx.x == 0){
        long guard = 0;
        while (__hip_atomic_load(bb + 288, __ATOMIC_RELAXED, __HIP_MEMORY_SCOPE_AGENT) < n){
            __builtin_amdgcn_s_sleep(2);
            if (++guard > 200000000L) break;
        }
        (void)__hip_atomic_load(bb + 288, __ATOMIC_ACQUIRE, __HIP_MEMORY_SCOPE_AGENT);
    }
    __syncthreads();
}

// ================= persistent encoder (r10, measured — unchanged) ============
__global__ __launch_bounds__(NTE, 1) void enc_persistent(
    const int* __restrict__ input_seq, const float* __restrict__ emb,
    const float* __restrict__ fWih, const float* __restrict__ fWhh,
    const float* __restrict__ fbih, const float* __restrict__ fbhh,
    const float* __restrict__ bWih, const float* __restrict__ bWhh,
    const float* __restrict__ bbih, const float* __restrict__ bbhh,
    float* enc_out, float* out_b, unsigned* bars)
{
    __shared__ float wlds[24*512];      // 48 KB weights
    __shared__ float shp[3*128*6];      // 9 KB partial exchange
    __shared__ float xh[32*XPITCH];     // 65 KB x/h row staging
    const int bk = blockIdx.x, tid = threadIdx.x;
    const int dir = bk & 1, jg = bk >> 1;
    const int b = tid & 31, jj = (tid>>5)&3, kh = tid>>7;
    const int j = jg*4 + jj;
    const unsigned grp = ((unsigned)jg) & 7u;

    const float *Wih = dir? bWih : fWih;
    const float *Whh = dir? bWhh : fWhh;
    const float *bih = dir? bbih : fbih;
    const float *bhh = dir? bbhh : fbhh;
    float* outp = dir? out_b : enc_out;
    unsigned* bar = bars + dir*1024;

    for (int r=0;r<24;r++){
        const int jr = jg*4 + (r/6);
        const int g  = r % 6;
        const float* src = (g<3) ? (Wih + ((size_t)g*H + jr)*H)
                                 : (Whh + ((size_t)(g-3)*H + jr)*H);
        for (int k=tid;k<H;k+=NTE) wlds[r*512+k] = src[k];
    }
    __syncthreads();

    const float4* wx0 = (const float4*)(wlds + (jj*6+0)*512 + kh*128);
    const float4* wx1 = (const float4*)(wlds + (jj*6+1)*512 + kh*128);
    const float4* wx2 = (const float4*)(wlds + (jj*6+2)*512 + kh*128);
    const float4* wh0 = (const float4*)(wlds + (jj*6+3)*512 + kh*128);
    const float4* wh1 = (const float4*)(wlds + (jj*6+4)*512 + kh*128);
    const float4* wh2 = (const float4*)(wlds + (jj*6+5)*512 + kh*128);
    const float bi_r = bih[j], bi_z = bih[H+j], bi_n = bih[2*H+j];
    const float bh_r = bhh[j], bh_z = bhh[H+j], bh_n = bhh[2*H+j];

    for (int t=0; t<S; t++){
        const int pos  = dir ? (S-1-t) : t;
        const int hpos = dir ? (S-t)   : (t-1);

        // ---- stage x rows (coalesced: 128 consecutive threads per row) ----
        #pragma unroll
        for (int it=0; it<8; ++it){
            const int idx = it*NTE + tid;
            const int bb = idx >> 7, c = idx & 127;
            const int tok = input_seq[bb*S + pos];
            ((float4*)(xh + bb*XPITCH))[c] =
                ((const float4*)(emb + (size_t)tok*H))[c];
        }
        __syncthreads();

        // x-part BEFORE the wait (overlaps barrier skew)
        float ir=0.f, iz=0.f, in_=0.f;
        {
            const float4* x4 = (const float4*)(xh + b*XPITCH + kh*128);
            #pragma unroll 8
            for (int k=0;k<32;k++){
                const float4 xv = x4[k];
                ir  = dot4(ir , xv, wx0[k]);
                iz  = dot4(iz , xv, wx1[k]);
                in_ = dot4(in_, xv, wx2[k]);
            }
        }

        if (t > 0) gbar_wait(bar, (unsigned)t);   // ends with __syncthreads

        float hr=0.f, hz=0.f, hn=0.f, hprev = 0.f;
        if (t > 0){
            // ---- stage h rows (coalesced) ----
            #pragma unroll
            for (int it=0; it<8; ++it){
                const int idx = it*NTE + tid;
                const int bb = idx >> 7, c = idx & 127;
                ((float4*)(xh + bb*XPITCH))[c] =
                    ((const float4*)(outp + ((size_t)bb*S + hpos)*H))[c];
            }
            __syncthreads();
            const float4* h4 = (const float4*)(xh + b*XPITCH + kh*128);
            #pragma unroll 8
            for (int k=0;k<32;k++){
                const float4 hv = h4[k];
                hr = dot4(hr, hv, wh0[k]);
                hz = dot4(hz, hv, wh1[k]);
                hn = dot4(hn, hv, wh2[k]);
            }
            hprev = xh[b*XPITCH + j];
        }
        if (kh){
            float* p = shp + ((kh-1)*128 + jj*32 + b)*6;
            p[0]=ir; p[1]=iz; p[2]=in_; p[3]=hr; p[4]=hz; p[5]=hn;
        }
        __syncthreads();
        if (!kh){
            #pragma unroll
            for (int q=0;q<3;q++){
                const float* p = shp + (q*128 + jj*32 + b)*6;
                ir+=p[0]; iz+=p[1]; in_+=p[2]; hr+=p[3]; hz+=p[4]; hn+=p[5];
            }
            const float r = sigmoidf_(ir + bi_r + hr + bh_r);
            const float z = sigmoidf_(iz + bi_z + hz + bh_z);
            const float n = tanhf(in_ + bi_n + r*(hn + bh_n));
            outp[((size_t)b*S + pos)*H + j] = (1.0f - z)*n + z*hprev;
        }
        gbar_arrive<16>(bar, grp, (unsigned)(t+1));
    }
}

// ================= persistent decoder (r11 + outW LDS pinning) ===============
__global__ __launch_bounds__(NTD, 1) void dec_persistent(
    const int* __restrict__ target_seq, const float* __restrict__ emb,
    const float* __restrict__ dWih, const float* __restrict__ dWhh,
    const float* __restrict__ dbih, const float* __restrict__ dbhh,
    const float* __restrict__ attW, const float* __restrict__ attb,
    const float* __restrict__ outW, const float* __restrict__ outBias,
    float* enc_out, const float* out_b,
    float* hdec, float* scores, float* ctxb, float* att_out,
    float* pm, float* ps, int* pidx, float* lossb,
    float* out, unsigned* bar)
{
    __shared__ __align__(16) float smem[128*33*4];      // 67.6 KB: L att-tile / scratch
    __shared__ float wg[12*512];                        // GRU weights: 2 j x 6 rows (24 KB)
    __shared__ __align__(16) float pinw[NPIN*PINP];     // 66 KB: pinned outW rows 0..31
    __shared__ float red_m[4][32], red_s[4][32];        // phase-L cross-wave reduce
    __shared__ int   red_i[4][32];
    __shared__ int sh_tok[B];
    const int bk = blockIdx.x, tid = threadIdx.x;
    const unsigned grp = (unsigned)bk & 7u;
    unsigned bn = 1;
#define GSYNC() do { gbar_arrive<32>(bar, grp, bn); gbar_wait(bar, bn); ++bn; } while(0)

    // stage GRU weights -> LDS (once)
    for (int r=0;r<12;r++){
        const int jr = bk*2 + (r/6);
        const int g  = r % 6;
        const float* src = (g<3) ? (dWih + ((size_t)g*H + jr)*H)
                                 : (dWhh + ((size_t)(g-3)*H + jr)*H);
        for (int k=tid;k<H;k+=NTD) wg[r*512+k] = src[k];
    }
    // pin first NPIN outW rows of this block's chunk -> LDS (once)
    if (bk < LCHUNK){
        for (int idx = tid; idx < NPIN*128; idx += NTD){
            const int row = idx >> 7, k4 = idx & 127;   // coalesced in k4
            ((float4*)(pinw + row*PINP))[k4] =
                ((const float4*)(outW + (size_t)(bk*LROWS + row)*H))[k4];
        }
    }

    // ---- phase A: hdec0 = hf_last + hb_last; loss init ----------------------
    {
        const int gid = bk*NTD + tid;
        if (gid < B*H){
            const int bb = gid >> 9, jq = gid & 511;
            hdec[gid] = enc_out[((size_t)bb*S + (S-1))*H + jq] + out_b[((size_t)bb*S)*H + jq];
        }
        if (bk==0 && tid<B) lossb[tid] = 0.0f;
    }
    GSYNC();

    // ---- phase B: combine enc_out += out_b ----------------------------------
    {
        float4* e4 = (float4*)enc_out; const float4* o4 = (const float4*)out_b;
        for (size_t i = (size_t)bk*NTD + tid; i < (size_t)B*S*H/4; i += (size_t)NB*NTD){
            float4 x = e4[i]; const float4 y = o4[i];
            x.x+=y.x; x.y+=y.y; x.z+=y.z; x.w+=y.w; e4[i]=x;
        }
    }
    GSYNC();

    const int gb = tid & 31, gj = (tid>>5)&1, gkq = tid>>6;   // gkq in 0..3
    const int jrow = bk*2 + gj;
    const float4* gwir = (const float4*)(wg + (gj*6+0)*512 + gkq*128);
    const float4* gwiz = (const float4*)(wg + (gj*6+1)*512 + gkq*128);
    const float4* gwin = (const float4*)(wg + (gj*6+2)*512 + gkq*128);
    const float4* gwhr = (const float4*)(wg + (gj*6+3)*512 + gkq*128);
    const float4* gwhz = (const float4*)(wg + (gj*6+4)*512 + gkq*128);
    const float4* gwhn = (const float4*)(wg + (gj*6+5)*512 + gkq*128);
    const float gbi_r = dbih[jrow], gbi_z = dbih[H+jrow], gbi_n = dbih[2*H+jrow];
    const float gbh_r = dbhh[jrow], gbh_z = dbhh[H+jrow], gbh_n = dbhh[2*H+jrow];
    // phase-P attW rows streamed from global (wp LDS dropped for pinning space)
    const float4* pwG = (const float4*)(attW + (size_t)jrow*(2*H)) + gkq*64;

    for (int t=0; t<T; t++){
        float* hin  = hdec + (size_t)(t&1)*B*H;
        float* hout = hdec + (size_t)((t+1)&1)*B*H;

        // ---------- phase G: merge(t-1) -> tokens (+loss, distributed), GRU --
        if (t == 0){
            if (tid < B) sh_tok[tid] = 1;     // SOS
        } else {
            const int mb = tid>>3, p = tid&7;
            float bv = -INFINITY; int ai = 0x7FFFFFFF;
            for (int c=p; c<LCHUNK; c+=8){
                const float v = pm[mb*LCHUNK + c];
                if (v > bv){ bv = v; ai = pidx[mb*LCHUNK + c]; }
            }
            #pragma unroll
            for (int m=1; m<8; m<<=1){
                const float ov = __shfl_xor(bv, m); const int oi = __shfl_xor(ai, m);
                if (ov > bv || (ov == bv && oi < ai)){ bv = ov; ai = oi; }
            }
            if (p==0) sh_tok[mb] = ai;
            if (bk == mb){   // loss for batch mb on block mb (was all on block 0)
                float mm = -INFINITY;
                for (int c=p; c<LCHUNK; c+=8) mm = fmaxf(mm, pm[mb*LCHUNK+c]);
                #pragma unroll
                for (int m=1;m<8;m<<=1) mm = fmaxf(mm, __shfl_xor(mm, m));
                float se = 0.0f;
                for (int c=p; c<LCHUNK; c+=8) se += ps[mb*LCHUNK+c]*expf(pm[mb*LCHUNK+c]-mm);
                #pragma unroll
                for (int m=1;m<8;m<<=1) se += __shfl_xor(se, m);
                const int tg = target_seq[mb*T + (t-1)];
                const float4* ar = (const float4*)(att_out + (size_t)mb*H) + p*16;
                const float4* wr = (const float4*)(outW + (size_t)tg*H) + p*16;
                float d = 0.0f;
                #pragma unroll
                for (int k=0;k<16;k++) d = dot4(d, ar[k], wr[k]);
                #pragma unroll
                for (int m=1;m<8;m<<=1) d += __shfl_xor(d, m);
                if (p==0) lossb[mb] += (mm + logf(se)) - (d + outBias[tg]);
            }
        }
        __syncthreads();
        {   // GRU: 2 j per block, K split 4x128, weights from LDS
            const int tokb = sh_tok[gb];
            const float4* x4 = (const float4*)(emb + (size_t)tokb*H + gkq*128);
            const float4* h4 = (const float4*)(hin + (size_t)gb*H + gkq*128);
            float ir=0.f, iz=0.f, in_=0.f, hr=0.f, hz=0.f, hn=0.f;
            #pragma unroll 4
            for (int k=0;k<32;k++){
                const float4 xv = x4[k], hv = h4[k];
                ir  = dot4(ir , xv, gwir[k]);
                iz  = dot4(iz , xv, gwiz[k]);
                in_ = dot4(in_, xv, gwin[k]);
                hr  = dot4(hr , hv, gwhr[k]);
                hz  = dot4(hz , hv, gwhz[k]);
                hn  = dot4(hn , hv, gwhn[k]);
            }
            if (gkq){
                float* pp = smem + ((gkq-1)*64 + gj*32 + gb)*6;
                pp[0]=ir; pp[1]=iz; pp[2]=in_; pp[3]=hr; pp[4]=hz; pp[5]=hn;
            }
            __syncthreads();
            if (!gkq){
                #pragma unroll
                for (int q=0;q<3;q++){
                    const float* pp = smem + (q*64 + gj*32 + gb)*6;
                    ir+=pp[0]; iz+=pp[1]; in_+=pp[2]; hr+=pp[3]; hz+=pp[4]; hn+=pp[5];
                }
                const float r = sigmoidf_(ir + gbi_r + hr + gbh_r);
                const float z = sigmoidf_(iz + gbi_z + hz + gbh_z);
                const float n = tanhf(in_ + gbi_n + r*(hn + gbh_n));
                const float hprev = hin[(size_t)gb*H + jrow];
                hout[(size_t)gb*H + jrow] = (1.0f - z)*n + z*hprev;
            }
        }
        GSYNC();

        // ---------- phase S (coalesced + row-pair ILP) -----------------------
        {
            const int bS = bk & 31, sg = bk >> 5;
            if (tid < 128)
                ((float4*)smem)[tid] = ((const float4*)(hout + (size_t)bS*H))[tid];
            __syncthreads();
            const int w = tid >> 6, lane = tid & 63;
            const float4 h0 = ((const float4*)smem)[lane];
            const float4 h1 = ((const float4*)smem)[64 + lane];
            const int sbase = sg*64 + w*16;
            #pragma unroll 4
            for (int i=0;i<16;i+=2){
                const int sA = sbase + i, sB = sA + 1;
                const float4* eA = (const float4*)(enc_out + ((size_t)bS*S + sA)*H);
                const float4* eB = (const float4*)(enc_out + ((size_t)bS*S + sB)*H);
                const float4 a0 = eA[lane], a1 = eA[64+lane];
                const float4 b0 = eB[lane], b1 = eB[64+lane];
                float a = dot4(dot4(0.f, a0, h0), a1, h1);
                float b = dot4(dot4(0.f, b0, h0), b1, h1);
                #pragma unroll
                for (int m=1;m<64;m<<=1){ a += __shfl_xor(a, m); b += __shfl_xor(b, m); }
                if (lane == 0){ scores[bS*S + sA] = a; scores[bS*S + sB] = b; }
            }
        }
        GSYNC();

        // ---------- phase C: softmax + ctx (4 independent acc chains) --------
        {
            const int bC = bk & 31, cg = bk >> 5;
            float* sh_w = smem; float* red = smem + 512; float* part = smem + 768;
            const float s0 = scores[bC*S + tid], s1 = scores[bC*S + tid + 256];
            red[tid] = fmaxf(s0,s1); __syncthreads();
            for (int off=128; off>0; off>>=1){ if (tid<off) red[tid]=fmaxf(red[tid],red[tid+off]); __syncthreads(); }
            const float M = red[0]; __syncthreads();
            const float e0 = expf(s0-M), e1 = expf(s1-M);
            red[tid] = e0+e1; __syncthreads();
            for (int off=128; off>0; off>>=1){ if (tid<off) red[tid]+=red[tid+off]; __syncthreads(); }
            const float inv = 1.0f/red[0];
            __syncthreads();
            sh_w[tid] = e0*inv; sh_w[tid+256] = e1*inv;
            __syncthreads();
            const int col = cg*64 + (tid & 63);
            const int sg2 = tid >> 6;
            const float* Ec = enc_out + (size_t)bC*S*H + col;
            float ac0=0.f, ac1=0.f, ac2=0.f, ac3=0.f;
            #pragma unroll 4
            for (int i=0;i<128;i+=4){
                const int sA = sg2 + 4*i, sB = sA+4, sC = sA+8, sD = sA+12;
                const float vA = Ec[(size_t)sA*H], vB = Ec[(size_t)sB*H];
                const float vC = Ec[(size_t)sC*H], vD = Ec[(size_t)sD*H];
                ac0 = fmaf(sh_w[sA], vA, ac0);
                ac1 = fmaf(sh_w[sB], vB, ac1);
                ac2 = fmaf(sh_w[sC], vC, ac2);
                ac3 = fmaf(sh_w[sD], vD, ac3);
            }
            part[tid] = (ac0+ac1)+(ac2+ac3); __syncthreads();
            if (tid < 64) ctxb[bC*512 + col] = part[tid]+part[tid+64]+part[tid+128]+part[tid+192];
        }
        GSYNC();

        // ---------- phase P: att_out = tanh([ctx,hn] @ attW.T + attb) ---------
        // attW streamed from global (broadcast across 32 lanes; 4 KB/block/step)
        {
            const float* act = (gkq < 2) ? (ctxb + (size_t)gb*512 + gkq*256)
                                         : (hout + (size_t)gb*H + (gkq-2)*256);
            const float4* a4 = (const float4*)act;
            float acc = 0.f;
            #pragma unroll 8
            for (int k=0;k<64;k++) acc = dot4(acc, a4[k], pwG[k]);
            if (gkq){
                smem[(gkq-1)*64 + gj*32 + gb] = acc;
            }
            __syncthreads();
            if (!gkq){
                acc += smem[0*64 + gj*32 + gb] + smem[1*64 + gj*32 + gb] + smem[2*64 + gj*32 + gb];
                att_out[(size_t)gb*H + jrow] = tanhf(acc + attb[jrow]);
            }
        }
        GSYNC();

        // ---------- phase L: logits; wave 0 from pinned LDS, waves 1-3 stream -
        if (bk < LCHUNK){
            float4* sh4 = (float4*)smem;                 // [128][33] float4
            for (int idx = tid; idx < 32*128; idx += NTD){
                const int k4 = idx & 127, bb = idx >> 7; // coalesced gmem read
                sh4[k4*33 + bb] = ((const float4*)att_out)[(size_t)bb*128 + k4];
            }
            __syncthreads();
            const int wid = tid >> 6, lane = tid & 63;
            const int rl = lane & 7, bl = lane >> 3;
            const int r0 = bk*LROWS + wid*32 + rl*4;     // 4 contiguous rows
            float acc[4][4];
            #pragma unroll
            for (int i=0;i<4;i++){ acc[i][0]=0.f; acc[i][1]=0.f; acc[i][2]=0.f; acc[i][3]=0.f; }

            if (wid == 0){
                // ---- pinned path: rows rl*4..rl*4+3 from LDS ----
                const float4* p0 = (const float4*)(pinw + (rl*4+0)*PINP);
                const float4* p1 = (const float4*)(pinw + (rl*4+1)*PINP);
                const float4* p2 = (const float4*)(pinw + (rl*4+2)*PINP);
                const float4* p3 = (const float4*)(pinw + (rl*4+3)*PINP);
                #pragma unroll 4
                for (int k=0;k<128;k++){
                    const float4 a0 = sh4[k*33 + bl*4 + 0];
                    const float4 a1 = sh4[k*33 + bl*4 + 1];
                    const float4 a2 = sh4[k*33 + bl*4 + 2];
                    const float4 a3 = sh4[k*33 + bl*4 + 3];
                    {   const float4 wv = p0[k];
                        acc[0][0]=dot4(acc[0][0],wv,a0); acc[0][1]=dot4(acc[0][1],wv,a1);
                        acc[0][2]=dot4(acc[0][2],wv,a2); acc[0][3]=dot4(acc[0][3],wv,a3); }
                    {   const float4 wv = p1[k];
                        acc[1][0]=dot4(acc[1][0],wv,a0); acc[1][1]=dot4(acc[1][1],wv,a1);
                        acc[1][2]=dot4(acc[1][2],wv,a2); acc[1][3]=dot4(acc[1][3],wv,a3); }
                    {   const float4 wv = p2[k];
                        acc[2][0]=dot4(acc[2][0],wv,a0); acc[2][1]=dot4(acc[2][1],wv,a1);
                        acc[2][2]=dot4(acc[2][2],wv,a2); acc[2][3]=dot4(acc[2][3],wv,a3); }
                    {   const float4 wv = p3[k];
                        acc[3][0]=dot4(acc[3][0],wv,a0); acc[3][1]=dot4(acc[3][1],wv,a1);
                        acc[3][2]=dot4(acc[3][2],wv,a2); acc[3][3]=dot4(acc[3][3],wv,a3); }
                }
            } else {
                // ---- streamed path: 2-stage register pipeline (r11) ----
                const float4* w0 = (const float4*)(outW + (size_t)(r0+0)*H);
                const float4* w1 = (const float4*)(outW + (size_t)(r0+1)*H);
                const float4* w2 = (const float4*)(outW + (size_t)(r0+2)*H);
                const float4* w3 = (const float4*)(outW + (size_t)(r0+3)*H);
                float4 A0[4],A1[4],A2[4],A3[4], B0[4],B1[4],B2[4],B3[4];
                #pragma unroll
                for (int kk=0;kk<4;kk++){ A0[kk]=w0[kk]; A1[kk]=w1[kk]; A2[kk]=w2[kk]; A3[kk]=w3[kk]; }
                for (int kc=0; kc<16; kc++){
                    const int kbB = kc*8 + 4;
                    #pragma unroll
                    for (int kk=0;kk<4;kk++){ B0[kk]=w0[kbB+kk]; B1[kk]=w1[kbB+kk]; B2[kk]=w2[kbB+kk]; B3[kk]=w3[kbB+kk]; }
                    #pragma unroll
                    for (int kk=0;kk<4;kk++){
                        const int k = kc*8 + kk;
                        const float4 a0 = sh4[k*33 + bl*4 + 0];
                        const float4 a1 = sh4[k*33 + bl*4 + 1];
                        const float4 a2 = sh4[k*33 + bl*4 + 2];
                        const float4 a3 = sh4[k*33 + bl*4 + 3];
                        acc[0][0]=dot4(acc[0][0],A0[kk],a0); acc[0][1]=dot4(acc[0][1],A0[kk],a1);
                        acc[0][2]=dot4(acc[0][2],A0[kk],a2); acc[0][3]=dot4(acc[0][3],A0[kk],a3);
                        acc[1][0]=dot4(acc[1][0],A1[kk],a0); acc[1][1]=dot4(acc[1][1],A1[kk],a1);
                        acc[1][2]=dot4(acc[1][2],A1[kk],a2); acc[1][3]=dot4(acc[1][3],A1[kk],a3);
                        acc[2][0]=dot4(acc[2][0],A2[kk],a0); acc[2][1]=dot4(acc[2][1],A2[kk],a1);
                        acc[2][2]=dot4(acc[2][2],A2[kk],a2); acc[2][3]=dot4(acc[2][3],A2[kk],a3);
                        acc[3][0]=dot4(acc[3][0],A3[kk],a0); acc[3][1]=dot4(acc[3][1],A3[kk],a1);
                        acc[3][2]=dot4(acc[3][2],A3[kk],a2); acc[3][3]=dot4(acc[3][3],A3[kk],a3);
                    }
                    if (kc < 15){
                        const int kbA = kc*8 + 8;
                        #pragma unroll
                        for (int kk=0;kk<4;kk++){ A0[kk]=w0[kbA+kk]; A1[kk]=w1[kbA+kk]; A2[kk]=w2[kbA+kk]; A3[kk]=w3[kbA+kk]; }
                    }
                    #pragma unroll
                    for (int kk=0;kk<4;kk++){
                        const int k = kc*8 + 4 + kk;
                        const float4 a0 = sh4[k*33 + bl*4 + 0];
                        const float4 a1 = sh4[k*33 + bl*4 + 1];
                        const float4 a2 = sh4[k*33 + bl*4 + 2];
                        const float4 a3 = sh4[k*33 + bl*4 + 3];
                        acc[0][0]=dot4(acc[0][0],B0[kk],a0); acc[0][1]=dot4(acc[0][1],B0[kk],a1);
                        acc[0][2]=dot4(acc[0][2],B0[kk],a2); acc[0][3]=dot4(acc[0][3],B0[kk],a3);
                        acc[1][0]=dot4(acc[1][0],B1[kk],a0); acc[1][1]=dot4(acc[1][1],B1[kk],a1);
                        acc[1][2]=dot4(acc[1][2],B1[kk],a2); acc[1][3]=dot4(acc[1][3],B1[kk],a3);
                        acc[2][0]=dot4(acc[2][0],B2[kk],a0); acc[2][1]=dot4(acc[2][1],B2[kk],a1);
                        acc[2][2]=dot4(acc[2][2],B2[kk],a2); acc[2][3]=dot4(acc[2][3],B2[kk],a3);
                        acc[3][0]=dot4(acc[3][0],B3[kk],a0); acc[3][1]=dot4(acc[3][1],B3[kk],a1);
                        acc[3][2]=dot4(acc[3][2],B3[kk],a2); acc[3][3]=dot4(acc[3][3],B3[kk],a3);
                    }
                }
            }

            const float bs0 = outBias[r0], bs1 = outBias[r0+1], bs2 = outBias[r0+2], bs3 = outBias[r0+3];
            #pragma unroll
            for (int j=0;j<4;j++){
                const float l0 = acc[0][j]+bs0, l1 = acc[1][j]+bs1, l2 = acc[2][j]+bs2, l3 = acc[3][j]+bs3;
                float M = l0; int bi = r0;                       // first-max tie-break
                if (l1 > M){ M=l1; bi=r0+1; }
                if (l2 > M){ M=l2; bi=r0+2; }
                if (l3 > M){ M=l3; bi=r0+3; }
                float Ssum = expf(l0-M)+expf(l1-M)+expf(l2-M)+expf(l3-M);
                #pragma unroll
                for (int m=1;m<8;m<<=1){                         // combine rl lanes
                    const float oM = __shfl_xor(M, m);
                    const float oS = __shfl_xor(Ssum, m);
                    const int   oI = __shfl_xor(bi, m);
                    const float nM = fmaxf(M, oM);
                    const float nS = Ssum*expf(M-nM) + oS*expf(oM-nM);
                    if (oM > M || (oM == M && oI < bi)) bi = oI;
                    M = nM; Ssum = nS;
                }
                if (rl == 0){
                    red_m[wid][bl*4+j] = M;
                    red_s[wid][bl*4+j] = Ssum;
                    red_i[wid][bl*4+j] = bi;
                }
            }
            __syncthreads();
            if (tid < 32){                                       // combine 4 waves
                float M = red_m[0][tid], Ssum = red_s[0][tid]; int bi = red_i[0][tid];
                #pragma unroll
                for (int w=1; w<4; w++){
                    const float oM = red_m[w][tid], oS = red_s[w][tid]; const int oI = red_i[w][tid];
                    const float nM = fmaxf(M, oM);
                    const float nS = Ssum*expf(M-nM) + oS*expf(oM-nM);
                    if (oM > M || (oM == M && oI < bi)) bi = oI;
                    M = nM; Ssum = nS;
                }
                pm[tid*LCHUNK + bk] = M;
                ps[tid*LCHUNK + bk] = Ssum;
                pidx[tid*LCHUNK + bk] = bi;
            }
        }
        GSYNC();
    }

    // ---- epilogue: block 0 computes loss(T-1) and the final mean -------------
    if (bk == 0){
        const int mb = tid>>3, p = tid&7;
        float mm = -INFINITY;
        for (int c=p; c<LCHUNK; c+=8) mm = fmaxf(mm, pm[mb*LCHUNK+c]);
        #pragma unroll
        for (int m=1;m<8;m<<=1) mm = fmaxf(mm, __shfl_xor(mm, m));
        float se = 0.0f;
        for (int c=p; c<LCHUNK; c+=8) se += ps[mb*LCHUNK+c]*expf(pm[mb*LCHUNK+c]-mm);
        #pragma unroll
        for (int m=1;m<8;m<<=1) se += __shfl_xor(se, m);
        const int tg = target_seq[mb*T + (T-1)];
        const float4* ar = (const float4*)(att_out + (size_t)mb*H) + p*16;
        const float4* wr = (const float4*)(outW + (size_t)tg*H) + p*16;
        float d = 0.0f;
        #pragma unroll
        for (int k=0;k<16;k++) d = dot4(d, ar[k], wr[k]);
        #pragma unroll
        for (int m=1;m<8;m<<=1) d += __shfl_xor(d, m);
        if (p==0) lossb[mb] += (mm + logf(se)) - (d + outBias[tg]);
        __syncthreads();
        if (tid < B){
            float v = lossb[tid];
            for (int off=16; off>0; off>>=1) v += __shfl_down(v, off);
            if (tid == 0) out[0] = v / (float)(B*T);
        }
    }
#undef GSYNC
}

extern "C" void kernel_launch(void* const* d_in, const int* in_sizes, int n_in,
                              void* d_out, int out_size, void* d_ws, size_t ws_size,
                              hipStream_t stream)
{
    const int*   input_seq  = (const int*)  d_in[0];
    const int*   target_seq = (const int*)  d_in[1];
    const float* emb    = (const float*)d_in[2];
    const float* efWih  = (const float*)d_in[3];
    const float* efWhh  = (const float*)d_in[4];
    const float* efbih  = (const float*)d_in[5];
    const float* efbhh  = (const float*)d_in[6];
    const float* ebWih  = (const float*)d_in[7];
    const float* ebWhh  = (const float*)d_in[8];
    const float* ebbih  = (const float*)d_in[9];
    const float* ebbhh  = (const float*)d_in[10];
    const float* dWih   = (const float*)d_in[11];
    const float* dWhh   = (const float*)d_in[12];
    const float* dbih   = (const float*)d_in[13];
    const float* dbhh   = (const float*)d_in[14];
    const float* attW   = (const float*)d_in[15];
    const float* attb   = (const float*)d_in[16];
    const float* outW   = (const float*)d_in[17];
    const float* outBias= (const float*)d_in[18];

    // workspace layout (floats); barrier region = 3 instances x 1024 uints
    float* ws      = (float*)d_ws;
    unsigned* bars = (unsigned*)ws;
    float* enc_out = ws + 4096;                             // B*S*H
    float* outb    = enc_out + (size_t)B*S*H;               // B*S*H
    float* scores  = outb    + (size_t)B*S*H;               // B*S
    float* ctxb    = scores  + (size_t)B*S;                 // B*512
    float* attout  = ctxb    + (size_t)B*512;               // B*H
    float* pm      = attout  + (size_t)B*H;                 // B*LCHUNK
    float* ps      = pm      + (size_t)B*LCHUNK;            // B*LCHUNK
    int*   pidx    = (int*)(ps + (size_t)B*LCHUNK);         // B*LCHUNK
    float* hdec    = (float*)(pidx + (size_t)B*LCHUNK);     // 2*B*H
    float* lossb   = hdec    + (size_t)2*B*H;               // B

    hipMemsetAsync(bars, 0, 16384, stream);

    enc_persistent<<<NB, NTE, 0, stream>>>(input_seq, emb,
        efWih, efWhh, efbih, efbhh, ebWih, ebWhh, ebbih, ebbhh,
        enc_out, outb, bars);

    dec_persistent<<<NB, NTD, 0, stream>>>(target_seq, emb,
        dWih, dWhh, dbih, dbhh, attW, attb, outW, outBias,
        enc_out, outb, hdec, scores, ctxb, attout,
        pm, ps, pidx, lossb, (float*)d_out, bars + 2048);
}